// Round 10
// baseline (585.564 us; speedup 1.0000x reference)
//
#include <hip/hip_runtime.h>
#include <math.h>

// Bit-exactness contract (DO NOT change any arithmetic):
// - reference means come from f32 sequential per-cluster sums in element order
//   (np.add.at semantics); reproduced via stable partition + one serial f32
//   add chain per cluster, __fadd_rn in element order.
// - all downstream math in deterministic f32 with numpy's exact op order.
// Round 9 (resubmit; GPU acquisition timeout):
// (a) chain_k — wave 0 isolated from staging (no global loads in the
// chain wave's instruction stream), ping-pong register groups with zero
// copies; min/max computed during staging (moved out of count_k).
// (b) count_k — reads only vr, 1 LDS atomic/element, per-wave histograms.
// No numerical change anywhere.

constexpr int NC   = 256;
constexpr int TILE = 16384;             // elements per tile (n multiple of TILE)

// ---------------- workspace layout (bytes) ----------------
// [0, NT*NC*4)      tileCnt  : per-tile cluster counts -> exclusive prefixes
// A = NT*NC*4 (1MB at n=16.7M):
// [A      , A+1024) cnt      : u32[256] total per cluster
// [A+1024 , A+2048) base     : u32[256] cluster start offsets
// [A+2048 , A+3072) vmn      : f32[256] cluster min
// [A+3072 , A+4096) vmx      : f32[256] cluster max
// [A+4096 , A+5120) csum     : f32[256] sequential-order f32 cluster sums
// [A+5120 , A+9216) params   : float4[256] {vmin, vmax, f0, f1}
// Partitioned pr (64MB) lives in d_out, consumed by chain_k before apply_k
// overwrites it.

// Pass 1: per-tile cluster histogram (vr only; min/max moved to chain_k).
__global__ __launch_bounds__(256) void count_k(const int* __restrict__ vr,
                                               unsigned* __restrict__ tileCnt) {
    constexpr int NW = 4;
    __shared__ unsigned whist[NW][NC];
    const int t = blockIdx.x;
    const int tid = threadIdx.x;
    const int w = tid >> 6, lane = tid & 63;
    for (int j = tid; j < NW * NC; j += 256) ((unsigned*)whist)[j] = 0u;
    __syncthreads();

    const int qbase = t * TILE + w * (TILE / NW);
    const int4* vq4 = (const int4*)(vr + qbase);
    for (int i = lane; i < TILE / NW / 4; i += 64) {
        int4 v = vq4[i];
        atomicAdd(&whist[w][v.x & 255], 1u);
        atomicAdd(&whist[w][v.y & 255], 1u);
        atomicAdd(&whist[w][v.z & 255], 1u);
        atomicAdd(&whist[w][v.w & 255], 1u);
    }
    __syncthreads();
    tileCnt[t * NC + tid] = whist[0][tid] + whist[1][tid] + whist[2][tid] + whist[3][tid];
}

// Pass 2a: per-cluster exclusive prefix across tiles (block c = cluster c).
__global__ __launch_bounds__(256) void colscan_k(unsigned* __restrict__ tileCnt,
                                                 int nt,
                                                 unsigned* __restrict__ cnt) {
    __shared__ unsigned th_sum[256];
    __shared__ unsigned ex[257];
    const int c = blockIdx.x;
    const int tid = threadIdx.x;
    const int per = nt / 256;            // tiles per thread (<= 8)
    unsigned loc[8];
    unsigned run = 0;
    for (int k = 0; k < per; ++k) {
        loc[k] = tileCnt[(tid * per + k) * NC + c];
        run += loc[k];
    }
    th_sum[tid] = run;
    __syncthreads();
    if (tid == 0) {
        unsigned a = 0;
        for (int j = 0; j < 256; ++j) { ex[j] = a; a += th_sum[j]; }
        ex[256] = a;
    }
    __syncthreads();
    unsigned r2 = ex[tid];
    for (int k = 0; k < per; ++k) {
        unsigned x = loc[k];
        tileCnt[(tid * per + k) * NC + c] = r2;
        r2 += x;
    }
    if (tid == 0) cnt[c] = ex[256];
}

// Pass 2b: exclusive scan of cluster totals -> base offsets (tiny).
__global__ __launch_bounds__(64) void base_k(const unsigned* __restrict__ cnt,
                                             unsigned* __restrict__ baseArr) {
    if (threadIdx.x == 0) {
        unsigned a = 0;
        for (int j = 0; j < NC; ++j) { baseArr[j] = a; a += cnt[j]; }
    }
}

// Pass 3: stable partition via LDS binning + coalesced flush.
// Order within cluster: tiles (global prefix) > waves (in-tile prefix) >
// groups (sequential per wave) > lanes (ballot rank). All preserved.
__global__ __launch_bounds__(256) void scatter_k(const float* __restrict__ pr,
                                                 const int* __restrict__ vr,
                                                 const unsigned* __restrict__ tilePre,
                                                 const unsigned* __restrict__ baseArr,
                                                 float* __restrict__ srt) {
    constexpr int NW = 4;                // waves per block
    constexpr int QT = TILE / NW;        // elements per wave
    __shared__ float bins[TILE];         // 64KB, cluster-major within tile
    __shared__ unsigned whist[NW][NC];   // counts -> per-wave exclusive offsets
    __shared__ unsigned wcur[NW][NC];
    __shared__ unsigned binStart[NC + 1];
    const int t = blockIdx.x;
    const int tid = threadIdx.x;
    const int w = tid >> 6, lane = tid & 63;

    for (int j = tid; j < NW * NC; j += 256) ((unsigned*)whist)[j] = 0u;
    __syncthreads();

    // Phase A: per-wave histogram of its quarter
    const int qbase = t * TILE + w * QT;
    const int4* vq4 = (const int4*)(vr + qbase);
    for (int i = lane; i < QT / 4; i += 64) {
        int4 v = vq4[i];
        atomicAdd(&whist[w][v.x & 255], 1u);
        atomicAdd(&whist[w][v.y & 255], 1u);
        atomicAdd(&whist[w][v.z & 255], 1u);
        atomicAdd(&whist[w][v.w & 255], 1u);
    }
    __syncthreads();

    // Phase B: across-wave exclusive offsets + tile totals (thread c = cluster c)
    {
        const int c = tid;
        unsigned off = 0;
        #pragma unroll
        for (int ww = 0; ww < NW; ++ww) {
            unsigned x = whist[ww][c];
            whist[ww][c] = off;          // per-wave exclusive offset within cluster
            off += x;
        }
        binStart[c] = off;               // tile total for cluster c (scanned below)
    }
    __syncthreads();
    if (tid == 0) {
        unsigned a = 0;
        for (int j = 0; j < NC; ++j) { unsigned x = binStart[j]; binStart[j] = a; a += x; }
        binStart[NC] = a;                // == TILE
    }
    __syncthreads();
    {
        const int c = tid;
        #pragma unroll
        for (int ww = 0; ww < NW; ++ww) wcur[ww][c] = binStart[c] + whist[ww][c];
    }
    __syncthreads();

    // Phase C: stable ballot-ranked binning (groups in element order per wave)
    for (int g = 0; g < QT / 64; ++g) {
        int idx = qbase + g * 64 + lane;
        int v   = vr[idx] & 255;
        float p = pr[idx];
        unsigned long long m = ~0ull;
        #pragma unroll
        for (int b = 0; b < 8; ++b) {
            unsigned long long bb = __ballot((v >> b) & 1);
            m &= ((v >> b) & 1) ? bb : ~bb;
        }
        unsigned long long below = (1ull << lane) - 1ull;
        int rank   = __popcll(m & below);
        int csame  = __popcll(m);
        int leader = __ffsll((unsigned long long)m) - 1;
        unsigned base = 0;
        if (rank == 0) base = atomicAdd(&wcur[w][v], (unsigned)csame);
        base = (unsigned)__shfl((int)base, leader, 64);
        bins[base + (unsigned)rank] = p;
    }
    __syncthreads();

    // Phase D: coalesced flush — each cluster's tile-run is contiguous in LDS
    // and contiguous in global.
    for (int c = w; c < NC; c += NW) {
        unsigned s0  = binStart[c];
        unsigned len = binStart[c + 1] - s0;
        unsigned dst = baseArr[c] + tilePre[t * NC + c];
        for (unsigned i = lane; i < len; i += 64)
            srt[dst + i] = bins[s0 + i];
    }
}

// Pass 4: serial f32 add chain per cluster (np.add.at order). One block per
// cluster. Staging (global->LDS, double-buffered 32KB chunks) is done ONLY by
// threads 64..255 so wave 0 never issues a global load; thread 0 runs the
// chain as a zero-copy ping-pong: load B(g+1), add A(g), load A(g+2),
// add B(g+1) — LDS latency hides under the 32 dependent adds. SAME add order.
// Staging threads also compute the cluster min/max (order-independent).
__global__ __launch_bounds__(256) void chain_k(const float* __restrict__ srt,
                                               const unsigned* __restrict__ baseArr,
                                               const unsigned* __restrict__ cnt,
                                               float* __restrict__ csum,
                                               float* __restrict__ vmnF,
                                               float* __restrict__ vmxF) {
    constexpr unsigned CH = 8192;        // floats per chunk (32KB); 2 bufs = 64KB
    __shared__ float buf[2][CH];
    __shared__ float redmn[256];
    __shared__ float redmx[256];
    const int c = blockIdx.x;
    const unsigned b = baseArr[c];
    const unsigned n = cnt[c];
    const int tid = threadIdx.x;
    const unsigned nch = (n + CH - 1) / CH;

    float lmn = INFINITY, lmx = -INFINITY;

    if (tid >= 64) {                     // preload chunk 0 (staging threads only)
        const unsigned len0 = n < CH ? n : CH;
        const float* src = srt + b;
        for (unsigned i = (unsigned)(tid - 64); i < len0; i += 192) {
            float x = src[i];
            buf[0][i] = x;
            lmn = fminf(lmn, x); lmx = fmaxf(lmx, x);
        }
    }
    __syncthreads();

    float s = 0.0f;
    for (unsigned ch = 0; ch < nch; ++ch) {
        const unsigned off = ch * CH;
        const unsigned len = (n - off) < CH ? (n - off) : CH;
        const unsigned nxt = off + CH;
        if (tid >= 64 && nxt < n) {      // prefetch next chunk into other buffer
            const unsigned len2 = (n - nxt) < CH ? (n - nxt) : CH;
            const float* src = srt + b + nxt;
            float* dst = buf[(ch + 1) & 1];
            for (unsigned i = (unsigned)(tid - 64); i < len2; i += 192) {
                float x = src[i];
                dst[i] = x;
                lmn = fminf(lmn, x); lmx = fmaxf(lmx, x);
            }
        }
        if (tid == 0) {                  // bit-exact sequential chain
            const float* p = buf[ch & 1];
            const float4* p4 = (const float4*)p;
            const unsigned ng = len >> 5;            // groups of 32 floats
            float4 A[8], B[8];
            auto LOAD8 = [&](float4 (&R)[8], unsigned g) {
                const float4* q = p4 + g * 8;
                #pragma unroll
                for (int k = 0; k < 8; ++k) R[k] = q[k];
            };
            auto ADD8 = [&](const float4 (&R)[8]) {
                #pragma unroll
                for (int k = 0; k < 8; ++k) {
                    s = __fadd_rn(s, R[k].x); s = __fadd_rn(s, R[k].y);
                    s = __fadd_rn(s, R[k].z); s = __fadd_rn(s, R[k].w);
                }
            };
            unsigned g = 0;
            if (ng) {
                LOAD8(A, 0);
                for (; g + 2 < ng; g += 2) {
                    LOAD8(B, g + 1);     // prefetch next group
                    ADD8(A);             // 32 dependent adds cover the latency
                    LOAD8(A, g + 2);
                    ADD8(B);
                }
                if (g + 1 < ng) { LOAD8(B, g + 1); ADD8(A); ADD8(B); g += 2; }
                else            { ADD8(A); g += 1; }
            }
            for (unsigned i = g << 5; i < len; ++i) s = __fadd_rn(s, p[i]);
        }
        __syncthreads();
    }

    redmn[tid] = lmn; redmx[tid] = lmx;
    __syncthreads();
    if (tid == 0) {
        float mn = INFINITY, mx = -INFINITY;
        for (int j = 64; j < 256; ++j) {
            mn = fminf(mn, redmn[j]);
            mx = fmaxf(mx, redmx[j]);
        }
        csum[c] = s;
        vmnF[c] = mn;
        vmxF[c] = mx;
    }
}

// Pass 5: f32 means -> validmin/NaN fix -> stable rank sort -> f0/f1 (exact
// numpy op order, unchanged).
__global__ __launch_bounds__(256) void finalize_k(const float* __restrict__ csum,
                                                  const unsigned* __restrict__ cnt,
                                                  const float* __restrict__ vmnF,
                                                  const float* __restrict__ vmxF,
                                                  float4* __restrict__ params) {
    __shared__ float vm[NC];
    __shared__ float vms[NC];
    __shared__ float s_validmin;
    const int c = threadIdx.x;

    float mean = __fdiv_rn(csum[c], (float)cnt[c]);   // empty -> 0/0 = NaN
    vm[c] = mean;
    __syncthreads();

    if (c == 0) {
        float mn = INFINITY;
        for (int j = 0; j < NC; ++j) {
            float x = vm[j];
            if (!__builtin_isnan(x) && x < mn) mn = x;
        }
        s_validmin = mn;
    }
    __syncthreads();
    float m = vm[c];
    if (__builtin_isnan(m)) m = __fmul_rn(s_validmin, 0.5f);
    __syncthreads();
    vm[c] = m;
    __syncthreads();

    int r = 0;
    for (int j = 0; j < NC; ++j) {
        float mj = vm[j];
        r += (mj < m) || (mj == m && j < c);
    }
    vms[r] = m;
    __syncthreads();

    float mid  = vms[r];
    float left = (r == 0) ? vms[0] : vms[r - 1];
    float f0 = __fdiv_rn(__fadd_rn(left, mid), 1.99f);
    float f1 = (r == NC - 1)
                 ? __fdiv_rn(__fadd_rn(mid, __fmul_rn(mid, 2.0f)), 2.01f)
                 : __fdiv_rn(__fadd_rn(mid, vms[r + 1]), 2.01f);

    float vmin = vmnF[c];
    float vmax = vmxF[c];
    bool ns = (vmin == vmax);
    params[c] = ns ? make_float4(0.0f, 1.0f, 0.0f, 1.0f)
                   : make_float4(vmin, vmax, f0, f1);
}

// Pass 6: elementwise, deterministic f32, numpy's exact op order (no FMA).
__global__ __launch_bounds__(256) void apply_k(const float* __restrict__ pr,
                                               const int* __restrict__ vr,
                                               const float4* __restrict__ params,
                                               float* __restrict__ out, int n) {
    __shared__ float4 s_par[NC];
    for (int c = threadIdx.x; c < NC; c += blockDim.x) s_par[c] = params[c];
    __syncthreads();

    auto elem = [&](float p, int c) -> float {
        float4 par = s_par[c];
        float a   = __fsub_rn(p, par.x);        // pr - vmins_g
        float den = __fsub_rn(par.y, par.x);    // vmaxs_g - vmins_g
        float q   = __fdiv_rn(a, den);
        float df  = __fsub_rn(par.w, par.z);    // f1_g - f0_g
        float e   = __fmul_rn(q, df);
        float tmp = __fadd_rn(e, par.z);
        float scale = __fdiv_rn(p, tmp);
        if (!__builtin_isfinite(scale)) scale = 0.0f;
        return __fmul_rn(p, scale);
    };

    const int tid = blockIdx.x * blockDim.x + threadIdx.x;
    const int stride = gridDim.x * blockDim.x;
    const int n4 = n >> 2;
    const float4* pr4 = (const float4*)pr;
    const int4*   vr4 = (const int4*)vr;
    float4* out4 = (float4*)out;
    for (int i = tid; i < n4; i += stride) {
        float4 p = pr4[i];
        int4   v = vr4[i];
        float4 o;
        o.x = elem(p.x, v.x & 255);
        o.y = elem(p.y, v.y & 255);
        o.z = elem(p.z, v.z & 255);
        o.w = elem(p.w, v.w & 255);
        out4[i] = o;
    }
    for (int i = (n4 << 2) + tid; i < n; i += stride) out[i] = elem(pr[i], vr[i] & 255);
}

extern "C" void kernel_launch(void* const* d_in, const int* in_sizes, int n_in,
                              void* d_out, int out_size, void* d_ws, size_t ws_size,
                              hipStream_t stream) {
    const float* pr = (const float*)d_in[0];
    const int*   vr = (const int*)d_in[1];
    float* out = (float*)d_out;
    const int n  = in_sizes[0];          // 16777216
    const int nt = n / TILE;             // 1024

    char* ws = (char*)d_ws;
    const size_t A = (size_t)nt * NC * 4;
    unsigned* tileCnt = (unsigned*)(ws);
    unsigned* g_cnt   = (unsigned*)(ws + A);
    unsigned* g_base  = (unsigned*)(ws + A + 1024);
    float*    g_vmn   = (float*)   (ws + A + 2048);
    float*    g_vmx   = (float*)   (ws + A + 3072);
    float*    g_csum  = (float*)   (ws + A + 4096);
    float4*   g_par   = (float4*)  (ws + A + 5120);

    float* srt = out;   // 64MB scratch: partitioned pr, consumed before apply_k

    count_k<<<nt, 256, 0, stream>>>(vr, tileCnt);
    colscan_k<<<NC, 256, 0, stream>>>(tileCnt, nt, g_cnt);
    base_k<<<1, 64, 0, stream>>>(g_cnt, g_base);
    scatter_k<<<nt, 256, 0, stream>>>(pr, vr, tileCnt, g_base, srt);
    chain_k<<<NC, 256, 0, stream>>>(srt, g_base, g_cnt, g_csum, g_vmn, g_vmx);
    finalize_k<<<1, 256, 0, stream>>>(g_csum, g_cnt, g_vmn, g_vmx, g_par);
    apply_k<<<2048, 256, 0, stream>>>(pr, vr, g_par, out, n);
}